// Round 1
// 916.188 us; speedup vs baseline: 1.0607x; 1.0607x over previous
//
#include <hip/hip_runtime.h>
#include <hip/hip_bf16.h>

#define D_DIM 256
#define EPS_LN 1e-5f
#define NEG_SLOPE 0.2f

typedef __bf16 bf16x8 __attribute__((ext_vector_type(8)));
typedef unsigned short ushortx8 __attribute__((ext_vector_type(8)));
typedef unsigned short ushortx4 __attribute__((ext_vector_type(4)));
typedef float floatx4 __attribute__((ext_vector_type(4)));

__device__ inline unsigned short f2bf(float f) {
    __hip_bfloat16 h = __float2bfloat16(f);
    return __builtin_bit_cast(unsigned short, h);
}
__device__ inline float bf2f(unsigned short u) {
    unsigned int x = ((unsigned int)u) << 16;
    return __builtin_bit_cast(float, x);
}

// 16B-per-lane async global->LDS copy.  LDS dest is wave-uniform base +
// lane*16 (HW semantics); global src is per-lane (carries our swizzle).
__device__ __forceinline__ void async_copy16(const void* g, void* l) {
    __builtin_amdgcn_global_load_lds(
        (const __attribute__((address_space(1))) unsigned int*)g,
        (__attribute__((address_space(3))) unsigned int*)l, 16, 0, 0);
}

__device__ inline bf16x8 cvt_frag(float4 a, float4 b) {
    ushortx8 u;
    u[0] = f2bf(a.x); u[1] = f2bf(a.y); u[2] = f2bf(a.z); u[3] = f2bf(a.w);
    u[4] = f2bf(b.x); u[5] = f2bf(b.y); u[6] = f2bf(b.z); u[7] = f2bf(b.w);
    return __builtin_bit_cast(bf16x8, u);
}

// ---------------------------------------------------------------------------
// Transpose + bf16-convert three 256x256 weight matrices (64x65 LDS tile).
// ---------------------------------------------------------------------------
__global__ __launch_bounds__(256) void wtrans_kernel(
        const float* __restrict__ W0, const float* __restrict__ W1,
        const float* __restrict__ W2, unsigned short* __restrict__ T0,
        unsigned short* __restrict__ T1, unsigned short* __restrict__ T2) {
    const float* W = (blockIdx.y == 0) ? W0 : (blockIdx.y == 1) ? W1 : W2;
    unsigned short* T = (blockIdx.y == 0) ? T0 : (blockIdx.y == 1) ? T1 : T2;
    __shared__ float lds[64][65];
    const int tx = blockIdx.x & 3;
    const int ty = blockIdx.x >> 2;
    const int t = threadIdx.x;
    const int r = t >> 6;
    const int c = t & 63;
#pragma unroll
    for (int i = 0; i < 16; ++i) {
        int row = ty * 64 + r + i * 4;
        lds[r + i * 4][c] = W[row * 256 + tx * 64 + c];
    }
    __syncthreads();
#pragma unroll
    for (int i = 0; i < 16; ++i) {
        int orow = tx * 64 + r + i * 4;
        T[orow * 256 + ty * 64 + c] = f2bf(lds[c][r + i * 4]);
    }
}

// ---------------------------------------------------------------------------
// LayerNorm + ReLU, one wave per row of 256
// ---------------------------------------------------------------------------
__global__ __launch_bounds__(256) void ln_relu_kernel(
        const float* __restrict__ x, const float* __restrict__ g,
        const float* __restrict__ b, float* __restrict__ y, int nrows) {
    int row = blockIdx.x * 4 + (threadIdx.x >> 6);
    if (row >= nrows) return;
    int lane = threadIdx.x & 63;
    float4 v = ((const float4*)(x + (size_t)row * D_DIM))[lane];
    float s = v.x + v.y + v.z + v.w;
    float s2 = v.x * v.x + v.y * v.y + v.z * v.z + v.w * v.w;
#pragma unroll
    for (int m = 32; m >= 1; m >>= 1) {
        s += __shfl_xor(s, m, 64);
        s2 += __shfl_xor(s2, m, 64);
    }
    float mean = s * (1.f / D_DIM);
    float var = s2 * (1.f / D_DIM) - mean * mean;
    float rstd = rsqrtf(var + EPS_LN);
    float4 gv = ((const float4*)g)[lane];
    float4 bv = ((const float4*)b)[lane];
    float4 o;
    o.x = fmaxf((v.x - mean) * rstd * gv.x + bv.x, 0.f);
    o.y = fmaxf((v.y - mean) * rstd * gv.y + bv.y, 0.f);
    o.z = fmaxf((v.z - mean) * rstd * gv.z + bv.z, 0.f);
    o.w = fmaxf((v.w - mean) * rstd * gv.w + bv.w, 0.f);
    ((float4*)(y + (size_t)row * D_DIM))[lane] = o;
}

// ---------------------------------------------------------------------------
// bf16-MFMA GEMM: out[M,256] = A[M,256]@W + bias (+res).
// FULL-WIDTH tile 128x256 (grid.x = M/128 only): A panel read from HBM
// exactly ONCE (old 128x128 grid fetched each A panel per N-half on
// different XCDs).  4 waves, wave = 64x128 (4x8 of 16x16x32), 32 MFMA per
// barrier (2x the old structure).  A staged raw fp32 via global_load_lds
// (source-side XOR swizzle), W bf16 pre-transposed.  Double-buffered,
// one __syncthreads per K-iter.  LDS 64KB -> 2 blocks/CU.
// Epilogue restages C through LDS so stores are dwordx4-coalesced
// (old path: 2B/4B scalar stores + scalar res reads).
// ---------------------------------------------------------------------------
template <int OUT_BF16, int HAS_RES>
__global__ __launch_bounds__(256, 2) void gemm256_kernel(
        const float* __restrict__ A, const unsigned short* __restrict__ Wt,
        const float* __restrict__ bias, const float* __restrict__ res,
        void* __restrict__ out, int M) {
    __shared__ __attribute__((aligned(16))) char smem[65536];
    float* Asb = (float*)smem;                              // [2][128*32] f32
    unsigned short* Bsb = (unsigned short*)(smem + 32768);  // [2][256*32] bf16
    const int m0 = blockIdx.x * 128;
    const int t = threadIdx.x;
    const int lane = t & 63;
    const int wave = t >> 6;
    const int q = lane >> 4;
    const int l16 = lane & 15;
    const int wm = (wave & 1) * 64;
    const int wn = (wave >> 1) * 128;

    // A staging: 4 segments/wave, segment = 8 rows x 128B.
    const int rowLA = lane >> 3;                    // 0..7 within segment
    const int GA = (lane & 7) ^ (rowLA & 7);        // logical granule (16B)
    // B staging: 4 segments/wave, segment = 16 rows x 64B.
    const int rowLB = lane >> 2;                    // 0..15 within segment
    const int GB = (lane & 3) ^ ((lane >> 3) & 3);  // logical granule (16B)

    // per-lane A row ids, constant across K
    int arow[4];
#pragma unroll
    for (int i = 0; i < 4; ++i) {
        int rr = m0 + (wave * 4 + i) * 8 + rowLA;
        arow[i] = rr < M ? rr : (M - 1);            // clamp: valid mem, unused
    }

    auto stage = [&](int buf, int kt) {
#pragma unroll
        for (int i = 0; i < 4; ++i) {
            int s = wave * 4 + i;
            async_copy16(A + (size_t)arow[i] * 256 + kt * 32 + GA * 4,
                         Asb + buf * 4096 + s * 256);
        }
#pragma unroll
        for (int i = 0; i < 4; ++i) {
            int s = wave * 4 + i;
            int row = s * 16 + rowLB;
            async_copy16(Wt + (size_t)row * 256 + kt * 32 + GB * 8,
                         Bsb + buf * 8192 + s * 512);
        }
    };

    floatx4 acc[4][8] = {};

    stage(0, 0);
    __syncthreads();    // vmcnt(0) drain + barrier: buffer 0 ready

    for (int kt = 0; kt < 8; ++kt) {
        const int cur = kt & 1;
        if (kt < 7) stage(cur ^ 1, kt + 1);   // async, lands by next barrier
        bf16x8 af[4];
#pragma unroll
        for (int mi = 0; mi < 4; ++mi) {
            int r = wm + mi * 16 + l16;
            int P0 = (2 * q) ^ (r & 7);
            const float* base = Asb + cur * 4096 + r * 32;
            float4 f0 = *(const float4*)(base + P0 * 4);
            float4 f1 = *(const float4*)(base + (P0 ^ 1) * 4);
            af[mi] = cvt_frag(f0, f1);
        }
        bf16x8 bfr[8];
#pragma unroll
        for (int ni = 0; ni < 8; ++ni) {
            int r = wn + ni * 16 + l16;
            int P = q ^ ((r >> 1) & 3);
            bfr[ni] = __builtin_bit_cast(bf16x8,
                *(const ushortx8*)(Bsb + cur * 8192 + r * 32 + P * 8));
        }
#pragma unroll
        for (int mi = 0; mi < 4; ++mi)
#pragma unroll
            for (int ni = 0; ni < 8; ++ni)
                acc[mi][ni] = __builtin_amdgcn_mfma_f32_16x16x32_bf16(
                    af[mi], bfr[ni], acc[mi][ni], 0, 0, 0);
        __syncthreads();   // reads(cur) done before next iter overwrites cur
    }

    // ---- epilogue: restage through LDS for coalesced dwordx4 stores ----
    if (OUT_BF16) {
        unsigned short (*Cs)[256] = (unsigned short(*)[256])smem;  // 64 KB
#pragma unroll
        for (int mi = 0; mi < 4; ++mi)
#pragma unroll
            for (int ni = 0; ni < 8; ++ni) {
                int col = wn + ni * 16 + l16;
                float bcol = bias[col];
#pragma unroll
                for (int r = 0; r < 4; ++r) {
                    int row = wm + mi * 16 + q * 4 + r;
                    Cs[row][col] = f2bf(acc[mi][ni][r] + bcol);
                }
            }
        __syncthreads();
        unsigned short* po = (unsigned short*)out;
#pragma unroll
        for (int it = 0; it < 16; ++it) {
            int idx = it * 256 + t;         // 16B chunks, 32 per row
            int row = idx >> 5;
            int c = idx & 31;
            if (m0 + row < M)
                ((float4*)(po + (size_t)(m0 + row) * 256))[c] =
                    ((const float4*)&Cs[row][0])[c];
        }
    } else {
        float (*Cf)[256] = (float(*)[256])smem;  // 64 rows x 256 f32 = 64 KB
        float* po = (float*)out;
#pragma unroll
        for (int h = 0; h < 2; ++h) {
            __syncthreads();                 // previous half (or K-loop) done
            if (wm == h * 64) {
#pragma unroll
                for (int mi = 0; mi < 4; ++mi)
#pragma unroll
                    for (int ni = 0; ni < 8; ++ni) {
                        int col = wn + ni * 16 + l16;
                        float bcol = bias[col];
#pragma unroll
                        for (int r = 0; r < 4; ++r)
                            Cf[mi * 16 + q * 4 + r][col] =
                                acc[mi][ni][r] + bcol;
                    }
            }
            __syncthreads();
#pragma unroll
            for (int it = 0; it < 16; ++it) {
                int idx = it * 256 + t;     // 16B chunks, 64 per row
                int row = idx >> 6;
                int c = idx & 63;
                int grow = m0 + h * 64 + row;
                if (grow < M) {
                    float4 v = ((const float4*)&Cf[row][0])[c];
                    if (HAS_RES) {
                        float4 rv = ((const float4*)(res + (size_t)grow * 256))[c];
                        v.x += rv.x; v.y += rv.y; v.z += rv.z; v.w += rv.w;
                    }
                    ((float4*)(po + (size_t)grow * 256))[c] = v;
                }
            }
        }
    }
}

// ---------------------------------------------------------------------------
// CSR build: histogram, single-block scan, scatter (stores SOURCE ids)
// ---------------------------------------------------------------------------
__global__ void hist_kernel(const int* __restrict__ tgt, int* __restrict__ counts, int E) {
    int i = blockIdx.x * 256 + threadIdx.x;
    if (i < E) atomicAdd(&counts[tgt[i]], 1);
}

__global__ __launch_bounds__(1024) void scan_kernel(
        const int* __restrict__ counts, int* __restrict__ offs, int n) {
    __shared__ int lds[1024];
    int t = threadIdx.x;
    int CH = (n + 1023) >> 10;
    int beg = t * CH, end = min(beg + CH, n);
    int s = 0;
    for (int i = beg; i < end; ++i) s += counts[i];
    lds[t] = s;
    __syncthreads();
    for (int off = 1; off < 1024; off <<= 1) {
        int v = (t >= off) ? lds[t - off] : 0;
        __syncthreads();
        lds[t] += v;
        __syncthreads();
    }
    int run = lds[t] - s;
    for (int i = beg; i < end; ++i) { offs[i] = run; run += counts[i]; }
    if (t == 1023) offs[n] = lds[1023];
}

__global__ void scatter_kernel(const int* __restrict__ tgt, const int* __restrict__ src,
                               const int* __restrict__ offs, int* __restrict__ cursor,
                               int* __restrict__ slist, int E) {
    int i = blockIdx.x * 256 + threadIdx.x;
    if (i < E) {
        int tg = tgt[i];
        int p = atomicAdd(&cursor[tg], 1);
        slist[offs[tg] + p] = src[i];   // store source node id directly
    }
}

// ---------------------------------------------------------------------------
// Per-target fused: edge softmax + aggregation + gat_bias + residual + LN2 +
// relu.  One wave per target; lane l owns features 4l..4l+3 (head = l>>3);
// per-head dot via shfl_xor {1,2,4}.  2-deep slist prefetch + 1-deep row
// prefetch so the slist->row dependent chain never serializes an iteration.
// ---------------------------------------------------------------------------
__global__ __launch_bounds__(256) void aggregate_kernel(
        const unsigned short* __restrict__ xl, const float* __restrict__ xr,
        const float* __restrict__ prev, const int* __restrict__ slist,
        const int* __restrict__ offs, const float* __restrict__ att,
        const float* __restrict__ gbias, const float* __restrict__ g2,
        const float* __restrict__ b2, float* __restrict__ x_skip,
        float* __restrict__ h2, int nsp) {
    int tgt = blockIdx.x * 4 + (threadIdx.x >> 6);
    if (tgt >= nsp) return;
    int lane = threadIdx.x & 63;
    float4 xrv = ((const float4*)(xr + (size_t)tgt * D_DIM))[lane];
    float4 attv = ((const float4*)att)[lane];
    float acc0 = 0.f, acc1 = 0.f, acc2 = 0.f, acc3 = 0.f, den = 0.f;
    int beg = offs[tgt], end = offs[tgt + 1];

    ushortx4 row = {};
    int src_n = 0;
    if (beg < end) {
        int src = slist[beg];
        row = ((const ushortx4*)(xl + (size_t)src * D_DIM))[lane];
        if (beg + 1 < end) src_n = slist[beg + 1];
    }
    for (int i = beg; i < end; ++i) {
        int src_n2 = (i + 2 < end) ? slist[i + 2] : 0;
        ushortx4 row_n = {};
        if (i + 1 < end)
            row_n = ((const ushortx4*)(xl + (size_t)src_n * D_DIM))[lane];
        float x0 = bf2f(row[0]), x1 = bf2f(row[1]), x2 = bf2f(row[2]), x3 = bf2f(row[3]);
        float t0 = x0 + xrv.x, t1 = x1 + xrv.y, t2 = x2 + xrv.z, t3 = x3 + xrv.w;
        t0 = t0 > 0.f ? t0 : NEG_SLOPE * t0;
        t1 = t1 > 0.f ? t1 : NEG_SLOPE * t1;
        t2 = t2 > 0.f ? t2 : NEG_SLOPE * t2;
        t3 = t3 > 0.f ? t3 : NEG_SLOPE * t3;
        float p = t0 * attv.x + t1 * attv.y + t2 * attv.z + t3 * attv.w;
        p += __shfl_xor(p, 1, 64);
        p += __shfl_xor(p, 2, 64);
        p += __shfl_xor(p, 4, 64);
        float ex = __expf(p);
        den += ex;
        acc0 += ex * x0; acc1 += ex * x1; acc2 += ex * x2; acc3 += ex * x3;
        row = row_n; src_n = src_n2;
    }
    float rden = 1.f / (den + 1e-16f);
    float4 pv = ((const float4*)(prev + (size_t)tgt * D_DIM))[lane];
    float4 gb = ((const float4*)gbias)[lane];
    float v0 = pv.x + acc0 * rden + gb.x;
    float v1 = pv.y + acc1 * rden + gb.y;
    float v2 = pv.z + acc2 * rden + gb.z;
    float v3 = pv.w + acc3 * rden + gb.w;
    float s = v0 + v1 + v2 + v3;
    float s2 = v0 * v0 + v1 * v1 + v2 * v2 + v3 * v3;
#pragma unroll
    for (int m = 32; m >= 1; m >>= 1) {
        s += __shfl_xor(s, m, 64);
        s2 += __shfl_xor(s2, m, 64);
    }
    float mean = s * (1.f / D_DIM);
    float var = s2 * (1.f / D_DIM) - mean * mean;
    float rstd = rsqrtf(var + EPS_LN);
    float4 g2v = ((const float4*)g2)[lane];
    float4 b2v = ((const float4*)b2)[lane];
    float4 xs; xs.x = v0; xs.y = v1; xs.z = v2; xs.w = v3;
    ((float4*)(x_skip + (size_t)tgt * D_DIM))[lane] = xs;
    float4 h;
    h.x = fmaxf((v0 - mean) * rstd * g2v.x + b2v.x, 0.f);
    h.y = fmaxf((v1 - mean) * rstd * g2v.y + b2v.y, 0.f);
    h.z = fmaxf((v2 - mean) * rstd * g2v.z + b2v.z, 0.f);
    h.w = fmaxf((v3 - mean) * rstd * g2v.w + b2v.w, 0.f);
    ((float4*)(h2 + (size_t)tgt * D_DIM))[lane] = h;
}

// ---------------------------------------------------------------------------
extern "C" void kernel_launch(void* const* d_in, const int* in_sizes, int n_in,
                              void* d_out, int out_size, void* d_ws, size_t ws_size,
                              hipStream_t stream) {
    const float* proj = (const float*)d_in[0];
    const float* prev = (const float*)d_in[1];
    const float* Wl   = (const float*)d_in[2];
    const float* bl   = (const float*)d_in[3];
    const float* Wr   = (const float*)d_in[4];
    const float* br   = (const float*)d_in[5];
    const float* att  = (const float*)d_in[6];
    const float* gbias= (const float*)d_in[7];
    const float* ln1g = (const float*)d_in[8];
    const float* ln1b = (const float*)d_in[9];
    const float* ln2g = (const float*)d_in[10];
    const float* ln2b = (const float*)d_in[11];
    const float* Wm   = (const float*)d_in[12];
    const float* mb   = (const float*)d_in[13];
    const int* esrc   = (const int*)d_in[14];
    const int* etgt   = (const int*)d_in[15];

    const int NP = in_sizes[0] / D_DIM;   // 400000
    const int NS = in_sizes[1] / D_DIM;   // 40000
    const int E  = in_sizes[14];          // 400000

    char* base = (char*)d_ws;
    size_t off = 0;
    auto carve = [&](size_t bytes) {
        char* p = base + off;
        off += (bytes + 255) & ~(size_t)255;
        return p;
    };
    unsigned short* xl    = (unsigned short*)carve((size_t)NP * D_DIM * 2);
    float* x_agg          = (float*)carve((size_t)NS * D_DIM * 4);
    float* xr             = (float*)carve((size_t)NS * D_DIM * 4);
    float* x_skip         = (float*)carve((size_t)NS * D_DIM * 4);
    float* h2             = (float*)carve((size_t)NS * D_DIM * 4);
    unsigned short* Wt_l  = (unsigned short*)carve((size_t)D_DIM * D_DIM * 2);
    unsigned short* Wt_r  = (unsigned short*)carve((size_t)D_DIM * D_DIM * 2);
    unsigned short* Wt_m  = (unsigned short*)carve((size_t)D_DIM * D_DIM * 2);
    int* counts           = (int*)carve((size_t)NS * 4 * 2);
    int* cursor           = counts + NS;
    int* offs             = (int*)carve((size_t)(NS + 1) * 4);
    int* slist            = (int*)carve((size_t)E * 4);

    hipMemsetAsync(counts, 0, (size_t)NS * 4 * 2, stream);

    wtrans_kernel<<<dim3(16, 3), 256, 0, stream>>>(Wl, Wr, Wm, Wt_l, Wt_r, Wt_m);

    ln_relu_kernel<<<(NS + 3) / 4, 256, 0, stream>>>(prev, ln1g, ln1b, x_agg, NS);

    // xr = x_agg @ Wr + br (fp32 out)
    gemm256_kernel<0, 0><<<(NS + 127) / 128, 256, 0, stream>>>(
        x_agg, Wt_r, br, nullptr, (void*)xr, NS);

    // xl = proj @ Wl + bl (bf16 out)
    gemm256_kernel<1, 0><<<(NP + 127) / 128, 256, 0, stream>>>(
        proj, Wt_l, bl, nullptr, (void*)xl, NP);

    // CSR build
    hist_kernel<<<(E + 255) / 256, 256, 0, stream>>>(etgt, counts, E);
    scan_kernel<<<1, 1024, 0, stream>>>(counts, offs, NS);
    scatter_kernel<<<(E + 255) / 256, 256, 0, stream>>>(etgt, esrc, offs, cursor, slist, E);

    // fused edge softmax + aggregation + residual + LN2 + relu
    aggregate_kernel<<<(NS + 3) / 4, 256, 0, stream>>>(
        xl, xr, prev, slist, offs, att, gbias, ln2g, ln2b, x_skip, h2, NS);

    // out = x_skip + h2 @ mlp_W + mlp_b
    gemm256_kernel<0, 1><<<(NS + 127) / 128, 256, 0, stream>>>(
        h2, Wt_m, mb, x_skip, d_out, NS);
}

// Round 2
// 894.640 us; speedup vs baseline: 1.0863x; 1.0241x over previous
//
#include <hip/hip_runtime.h>
#include <hip/hip_bf16.h>

#define D_DIM 256
#define EPS_LN 1e-5f
#define NEG_SLOPE 0.2f

typedef __bf16 bf16x8 __attribute__((ext_vector_type(8)));
typedef unsigned short ushortx8 __attribute__((ext_vector_type(8)));
typedef unsigned short ushortx4 __attribute__((ext_vector_type(4)));
typedef float floatx4 __attribute__((ext_vector_type(4)));

__device__ inline unsigned short f2bf(float f) {
    __hip_bfloat16 h = __float2bfloat16(f);
    return __builtin_bit_cast(unsigned short, h);
}
__device__ inline float bf2f(unsigned short u) {
    unsigned int x = ((unsigned int)u) << 16;
    return __builtin_bit_cast(float, x);
}

// 16B-per-lane async global->LDS copy.  LDS dest is wave-uniform base +
// lane*16 (HW semantics); global src is per-lane (carries our swizzle).
__device__ __forceinline__ void async_copy16(const void* g, void* l) {
    __builtin_amdgcn_global_load_lds(
        (const __attribute__((address_space(1))) unsigned int*)g,
        (__attribute__((address_space(3))) unsigned int*)l, 16, 0, 0);
}

__device__ inline bf16x8 cvt_frag(float4 a, float4 b) {
    ushortx8 u;
    u[0] = f2bf(a.x); u[1] = f2bf(a.y); u[2] = f2bf(a.z); u[3] = f2bf(a.w);
    u[4] = f2bf(b.x); u[5] = f2bf(b.y); u[6] = f2bf(b.z); u[7] = f2bf(b.w);
    return __builtin_bit_cast(bf16x8, u);
}

// ---------------------------------------------------------------------------
// Transpose + bf16-convert three 256x256 weight matrices (64x65 LDS tile).
// ---------------------------------------------------------------------------
__global__ __launch_bounds__(256) void wtrans_kernel(
        const float* __restrict__ W0, const float* __restrict__ W1,
        const float* __restrict__ W2, unsigned short* __restrict__ T0,
        unsigned short* __restrict__ T1, unsigned short* __restrict__ T2) {
    const float* W = (blockIdx.y == 0) ? W0 : (blockIdx.y == 1) ? W1 : W2;
    unsigned short* T = (blockIdx.y == 0) ? T0 : (blockIdx.y == 1) ? T1 : T2;
    __shared__ float lds[64][65];
    const int tx = blockIdx.x & 3;
    const int ty = blockIdx.x >> 2;
    const int t = threadIdx.x;
    const int r = t >> 6;
    const int c = t & 63;
#pragma unroll
    for (int i = 0; i < 16; ++i) {
        int row = ty * 64 + r + i * 4;
        lds[r + i * 4][c] = W[row * 256 + tx * 64 + c];
    }
    __syncthreads();
#pragma unroll
    for (int i = 0; i < 16; ++i) {
        int orow = tx * 64 + r + i * 4;
        T[orow * 256 + ty * 64 + c] = f2bf(lds[c][r + i * 4]);
    }
}

// ---------------------------------------------------------------------------
// LayerNorm + ReLU, one wave per row of 256.  Output bf16 (it feeds the
// bf16-A GEMM path; rounding identical to the old in-GEMM f2bf).
// ---------------------------------------------------------------------------
__global__ __launch_bounds__(256) void ln_relu_kernel(
        const float* __restrict__ x, const float* __restrict__ g,
        const float* __restrict__ b, unsigned short* __restrict__ y, int nrows) {
    int row = blockIdx.x * 4 + (threadIdx.x >> 6);
    if (row >= nrows) return;
    int lane = threadIdx.x & 63;
    float4 v = ((const float4*)(x + (size_t)row * D_DIM))[lane];
    float s = v.x + v.y + v.z + v.w;
    float s2 = v.x * v.x + v.y * v.y + v.z * v.z + v.w * v.w;
#pragma unroll
    for (int m = 32; m >= 1; m >>= 1) {
        s += __shfl_xor(s, m, 64);
        s2 += __shfl_xor(s2, m, 64);
    }
    float mean = s * (1.f / D_DIM);
    float var = s2 * (1.f / D_DIM) - mean * mean;
    float rstd = rsqrtf(var + EPS_LN);
    float4 gv = ((const float4*)g)[lane];
    float4 bv = ((const float4*)b)[lane];
    ushortx4 o;
    o[0] = f2bf(fmaxf((v.x - mean) * rstd * gv.x + bv.x, 0.f));
    o[1] = f2bf(fmaxf((v.y - mean) * rstd * gv.y + bv.y, 0.f));
    o[2] = f2bf(fmaxf((v.z - mean) * rstd * gv.z + bv.z, 0.f));
    o[3] = f2bf(fmaxf((v.w - mean) * rstd * gv.w + bv.w, 0.f));
    ((ushortx4*)(y + (size_t)row * D_DIM))[lane] = o;
}

// ---------------------------------------------------------------------------
// bf16-MFMA GEMM: out[M,256] = A[M,256]@W + bias (+res).
// Full-width 128x256 tile, 4 waves, wave = 64x128 (4x8 of 16x16x32),
// global_load_lds staging with source-side XOR swizzle, double-buffered,
// one __syncthreads per K-iter.  A is fp32 (cvt at fragment read) or bf16
// (direct ushortx8 fragment read, B-style granules) per A_BF16.
// PERM: bf16 output rows scattered to inv[row] (CSR-ordered xl) so the
// aggregate kernel streams sequentially.
// Epilogue restages C through LDS for dwordx4-coalesced stores.
// ---------------------------------------------------------------------------
template <int OUT_BF16, int HAS_RES, int A_BF16, int PERM>
__global__ __launch_bounds__(256, 2) void gemm256_kernel(
        const void* __restrict__ Ain, const unsigned short* __restrict__ Wt,
        const float* __restrict__ bias, const float* __restrict__ res,
        const int* __restrict__ inv, void* __restrict__ out, int M) {
    __shared__ __attribute__((aligned(16))) char smem[65536];
    float* Asf = (float*)smem;                               // fp32-A: 32 KB
    unsigned short* As16 = (unsigned short*)smem;            // bf16-A: 16 KB
    unsigned short* Bsb = A_BF16 ? (unsigned short*)(smem + 16384)
                                 : (unsigned short*)(smem + 32768);
    const int m0 = blockIdx.x * 128;
    const int t = threadIdx.x;
    const int lane = t & 63;
    const int wave = t >> 6;
    const int q = lane >> 4;
    const int l16 = lane & 15;
    const int wm = (wave & 1) * 64;
    const int wn = (wave >> 1) * 128;

    // fp32-A staging: segment = 8 rows x 128B; 16 segs, 4/wave.
    const int rowLA = lane >> 3;
    const int GA = (lane & 7) ^ (rowLA & 7);
    // bf16 staging (A and B): segment = 16 rows x 64B; granule 16B.
    const int rowLB = lane >> 2;
    const int GB = (lane & 3) ^ ((lane >> 3) & 3);

    int arow[4];
    if constexpr (A_BF16) {
#pragma unroll
        for (int i = 0; i < 2; ++i) {
            int rr = m0 + (wave * 2 + i) * 16 + rowLB;
            arow[i] = rr < M ? rr : (M - 1);
        }
    } else {
#pragma unroll
        for (int i = 0; i < 4; ++i) {
            int rr = m0 + (wave * 4 + i) * 8 + rowLA;
            arow[i] = rr < M ? rr : (M - 1);
        }
    }

    auto stage = [&](int buf, int kt) {
        if constexpr (A_BF16) {
            const unsigned short* A = (const unsigned short*)Ain;
#pragma unroll
            for (int i = 0; i < 2; ++i) {
                int s = wave * 2 + i;
                async_copy16(A + (size_t)arow[i] * 256 + kt * 32 + GB * 8,
                             As16 + buf * 4096 + s * 512);
            }
        } else {
            const float* A = (const float*)Ain;
#pragma unroll
            for (int i = 0; i < 4; ++i) {
                int s = wave * 4 + i;
                async_copy16(A + (size_t)arow[i] * 256 + kt * 32 + GA * 4,
                             Asf + buf * 4096 + s * 256);
            }
        }
#pragma unroll
        for (int i = 0; i < 4; ++i) {
            int s = wave * 4 + i;
            int row = s * 16 + rowLB;
            async_copy16(Wt + (size_t)row * 256 + kt * 32 + GB * 8,
                         Bsb + buf * 8192 + s * 512);
        }
    };

    floatx4 acc[4][8] = {};

    stage(0, 0);
    __syncthreads();    // vmcnt(0) drain + barrier: buffer 0 ready

    for (int kt = 0; kt < 8; ++kt) {
        const int cur = kt & 1;
        if (kt < 7) stage(cur ^ 1, kt + 1);   // async, lands by next barrier
        bf16x8 af[4];
#pragma unroll
        for (int mi = 0; mi < 4; ++mi) {
            int r = wm + mi * 16 + l16;
            if constexpr (A_BF16) {
                int P = q ^ ((r >> 1) & 3);
                af[mi] = __builtin_bit_cast(bf16x8,
                    *(const ushortx8*)(As16 + cur * 4096 + r * 32 + P * 8));
            } else {
                int P0 = (2 * q) ^ (r & 7);
                const float* base = Asf + cur * 4096 + r * 32;
                float4 f0 = *(const float4*)(base + P0 * 4);
                float4 f1 = *(const float4*)(base + (P0 ^ 1) * 4);
                af[mi] = cvt_frag(f0, f1);
            }
        }
        bf16x8 bfr[8];
#pragma unroll
        for (int ni = 0; ni < 8; ++ni) {
            int r = wn + ni * 16 + l16;
            int P = q ^ ((r >> 1) & 3);
            bfr[ni] = __builtin_bit_cast(bf16x8,
                *(const ushortx8*)(Bsb + cur * 8192 + r * 32 + P * 8));
        }
#pragma unroll
        for (int mi = 0; mi < 4; ++mi)
#pragma unroll
            for (int ni = 0; ni < 8; ++ni)
                acc[mi][ni] = __builtin_amdgcn_mfma_f32_16x16x32_bf16(
                    af[mi], bfr[ni], acc[mi][ni], 0, 0, 0);
        __syncthreads();   // reads(cur) done before next iter overwrites cur
    }

    // ---- epilogue: restage through LDS for coalesced dwordx4 stores ----
    if (OUT_BF16) {
        unsigned short (*Cs)[256] = (unsigned short(*)[256])smem;  // 64 KB
#pragma unroll
        for (int mi = 0; mi < 4; ++mi)
#pragma unroll
            for (int ni = 0; ni < 8; ++ni) {
                int col = wn + ni * 16 + l16;
                float bcol = bias[col];
#pragma unroll
                for (int r = 0; r < 4; ++r) {
                    int row = wm + mi * 16 + q * 4 + r;
                    Cs[row][col] = f2bf(acc[mi][ni][r] + bcol);
                }
            }
        __syncthreads();
        unsigned short* po = (unsigned short*)out;
#pragma unroll
        for (int it = 0; it < 16; ++it) {
            int idx = it * 256 + t;         // 16B chunks, 32 per row
            int row = idx >> 5;
            int c = idx & 31;
            int grow = m0 + row;
            if (grow < M) {
                size_t orow = PERM ? (size_t)inv[grow] : (size_t)grow;
                ((float4*)(po + orow * 256))[c] =
                    ((const float4*)&Cs[row][0])[c];
            }
        }
    } else {
        float (*Cf)[256] = (float(*)[256])smem;  // 64 rows x 256 f32 = 64 KB
        float* po = (float*)out;
#pragma unroll
        for (int h = 0; h < 2; ++h) {
            __syncthreads();                 // previous half (or K-loop) done
            if (wm == h * 64) {
#pragma unroll
                for (int mi = 0; mi < 4; ++mi)
#pragma unroll
                    for (int ni = 0; ni < 8; ++ni) {
                        int col = wn + ni * 16 + l16;
                        float bcol = bias[col];
#pragma unroll
                        for (int r = 0; r < 4; ++r)
                            Cf[mi * 16 + q * 4 + r][col] =
                                acc[mi][ni][r] + bcol;
                    }
            }
            __syncthreads();
#pragma unroll
            for (int it = 0; it < 16; ++it) {
                int idx = it * 256 + t;     // 16B chunks, 64 per row
                int row = idx >> 6;
                int c = idx & 63;
                int grow = m0 + h * 64 + row;
                if (grow < M) {
                    float4 v = ((const float4*)&Cf[row][0])[c];
                    if (HAS_RES) {
                        float4 rv = ((const float4*)(res + (size_t)grow * 256))[c];
                        v.x += rv.x; v.y += rv.y; v.z += rv.z; v.w += rv.w;
                    }
                    ((float4*)(po + (size_t)grow * 256))[c] = v;
                }
            }
        }
    }
}

// ---------------------------------------------------------------------------
// CSR build: histogram, single-block scan, scatter -> inverse permutation
// inv[src] = CSR position (edge_src is a bijection: each source appears
// exactly once).  xl is then written CSR-ordered by the GEMM epilogue.
// ---------------------------------------------------------------------------
__global__ void hist_kernel(const int* __restrict__ tgt, int* __restrict__ counts, int E) {
    int i = blockIdx.x * 256 + threadIdx.x;
    if (i < E) atomicAdd(&counts[tgt[i]], 1);
}

__global__ __launch_bounds__(1024) void scan_kernel(
        const int* __restrict__ counts, int* __restrict__ offs, int n) {
    __shared__ int lds[1024];
    int t = threadIdx.x;
    int CH = (n + 1023) >> 10;
    int beg = t * CH, end = min(beg + CH, n);
    int s = 0;
    for (int i = beg; i < end; ++i) s += counts[i];
    lds[t] = s;
    __syncthreads();
    for (int off = 1; off < 1024; off <<= 1) {
        int v = (t >= off) ? lds[t - off] : 0;
        __syncthreads();
        lds[t] += v;
        __syncthreads();
    }
    int run = lds[t] - s;
    for (int i = beg; i < end; ++i) { offs[i] = run; run += counts[i]; }
    if (t == 1023) offs[n] = lds[1023];
}

__global__ void scatter_kernel(const int* __restrict__ tgt, const int* __restrict__ src,
                               const int* __restrict__ offs, int* __restrict__ cursor,
                               int* __restrict__ inv, int E) {
    int i = blockIdx.x * 256 + threadIdx.x;
    if (i < E) {
        int tg = tgt[i];
        int p = atomicAdd(&cursor[tg], 1);
        inv[src[i]] = offs[tg] + p;
    }
}

// ---------------------------------------------------------------------------
// Per-target fused: edge softmax + aggregation + gat_bias + residual + LN2 +
// relu.  xl is CSR-ordered: edges of target t are rows offs[t]..offs[t+1],
// read SEQUENTIALLY (no indirection, no dependent-load chain).  One wave
// per target; lane l owns features 4l..4l+3 (head = l>>3); per-head dot via
// shfl_xor {1,2,4}.  h2 written bf16 (feeds bf16-A GEMM).
// ---------------------------------------------------------------------------
__global__ __launch_bounds__(256) void aggregate_kernel(
        const unsigned short* __restrict__ xl, const float* __restrict__ xr,
        const float* __restrict__ prev, const int* __restrict__ offs,
        const float* __restrict__ att, const float* __restrict__ gbias,
        const float* __restrict__ g2, const float* __restrict__ b2,
        float* __restrict__ x_skip, unsigned short* __restrict__ h2, int nsp) {
    int tgt = blockIdx.x * 4 + (threadIdx.x >> 6);
    if (tgt >= nsp) return;
    int lane = threadIdx.x & 63;
    float4 xrv = ((const float4*)(xr + (size_t)tgt * D_DIM))[lane];
    float4 attv = ((const float4*)att)[lane];
    float acc0 = 0.f, acc1 = 0.f, acc2 = 0.f, acc3 = 0.f, den = 0.f;
    int beg = offs[tgt], end = offs[tgt + 1];

    ushortx4 row = {};
    if (beg < end)
        row = ((const ushortx4*)(xl + (size_t)beg * D_DIM))[lane];
    for (int i = beg; i < end; ++i) {
        ushortx4 row_n = {};
        if (i + 1 < end)
            row_n = ((const ushortx4*)(xl + (size_t)(i + 1) * D_DIM))[lane];
        float x0 = bf2f(row[0]), x1 = bf2f(row[1]), x2 = bf2f(row[2]), x3 = bf2f(row[3]);
        float t0 = x0 + xrv.x, t1 = x1 + xrv.y, t2 = x2 + xrv.z, t3 = x3 + xrv.w;
        t0 = t0 > 0.f ? t0 : NEG_SLOPE * t0;
        t1 = t1 > 0.f ? t1 : NEG_SLOPE * t1;
        t2 = t2 > 0.f ? t2 : NEG_SLOPE * t2;
        t3 = t3 > 0.f ? t3 : NEG_SLOPE * t3;
        float p = t0 * attv.x + t1 * attv.y + t2 * attv.z + t3 * attv.w;
        p += __shfl_xor(p, 1, 64);
        p += __shfl_xor(p, 2, 64);
        p += __shfl_xor(p, 4, 64);
        float ex = __expf(p);
        den += ex;
        acc0 += ex * x0; acc1 += ex * x1; acc2 += ex * x2; acc3 += ex * x3;
        row = row_n;
    }
    float rden = 1.f / (den + 1e-16f);
    float4 pv = ((const float4*)(prev + (size_t)tgt * D_DIM))[lane];
    float4 gb = ((const float4*)gbias)[lane];
    float v0 = pv.x + acc0 * rden + gb.x;
    float v1 = pv.y + acc1 * rden + gb.y;
    float v2 = pv.z + acc2 * rden + gb.z;
    float v3 = pv.w + acc3 * rden + gb.w;
    float s = v0 + v1 + v2 + v3;
    float s2 = v0 * v0 + v1 * v1 + v2 * v2 + v3 * v3;
#pragma unroll
    for (int m = 32; m >= 1; m >>= 1) {
        s += __shfl_xor(s, m, 64);
        s2 += __shfl_xor(s2, m, 64);
    }
    float mean = s * (1.f / D_DIM);
    float var = s2 * (1.f / D_DIM) - mean * mean;
    float rstd = rsqrtf(var + EPS_LN);
    float4 g2v = ((const float4*)g2)[lane];
    float4 b2v = ((const float4*)b2)[lane];
    float4 xs; xs.x = v0; xs.y = v1; xs.z = v2; xs.w = v3;
    ((float4*)(x_skip + (size_t)tgt * D_DIM))[lane] = xs;
    ushortx4 h;
    h[0] = f2bf(fmaxf((v0 - mean) * rstd * g2v.x + b2v.x, 0.f));
    h[1] = f2bf(fmaxf((v1 - mean) * rstd * g2v.y + b2v.y, 0.f));
    h[2] = f2bf(fmaxf((v2 - mean) * rstd * g2v.z + b2v.z, 0.f));
    h[3] = f2bf(fmaxf((v3 - mean) * rstd * g2v.w + b2v.w, 0.f));
    ((ushortx4*)(h2 + (size_t)tgt * D_DIM))[lane] = h;
}

// ---------------------------------------------------------------------------
extern "C" void kernel_launch(void* const* d_in, const int* in_sizes, int n_in,
                              void* d_out, int out_size, void* d_ws, size_t ws_size,
                              hipStream_t stream) {
    const float* proj = (const float*)d_in[0];
    const float* prev = (const float*)d_in[1];
    const float* Wl   = (const float*)d_in[2];
    const float* bl   = (const float*)d_in[3];
    const float* Wr   = (const float*)d_in[4];
    const float* br   = (const float*)d_in[5];
    const float* att  = (const float*)d_in[6];
    const float* gbias= (const float*)d_in[7];
    const float* ln1g = (const float*)d_in[8];
    const float* ln1b = (const float*)d_in[9];
    const float* ln2g = (const float*)d_in[10];
    const float* ln2b = (const float*)d_in[11];
    const float* Wm   = (const float*)d_in[12];
    const float* mb   = (const float*)d_in[13];
    const int* esrc   = (const int*)d_in[14];
    const int* etgt   = (const int*)d_in[15];

    const int NP = in_sizes[0] / D_DIM;   // 400000
    const int NS = in_sizes[1] / D_DIM;   // 40000
    const int E  = in_sizes[14];          // 400000

    char* base = (char*)d_ws;
    size_t off = 0;
    auto carve = [&](size_t bytes) {
        char* p = base + off;
        off += (bytes + 255) & ~(size_t)255;
        return p;
    };
    unsigned short* xl    = (unsigned short*)carve((size_t)E * D_DIM * 2);   // CSR-ordered
    unsigned short* x_agg = (unsigned short*)carve((size_t)NS * D_DIM * 2);
    float* xr             = (float*)carve((size_t)NS * D_DIM * 4);
    float* x_skip         = (float*)carve((size_t)NS * D_DIM * 4);
    unsigned short* h2    = (unsigned short*)carve((size_t)NS * D_DIM * 2);
    unsigned short* Wt_l  = (unsigned short*)carve((size_t)D_DIM * D_DIM * 2);
    unsigned short* Wt_r  = (unsigned short*)carve((size_t)D_DIM * D_DIM * 2);
    unsigned short* Wt_m  = (unsigned short*)carve((size_t)D_DIM * D_DIM * 2);
    int* counts           = (int*)carve((size_t)NS * 4 * 2);
    int* cursor           = counts + NS;
    int* offs             = (int*)carve((size_t)(NS + 1) * 4);
    int* inv              = (int*)carve((size_t)NP * 4);

    hipMemsetAsync(counts, 0, (size_t)NS * 4 * 2, stream);

    wtrans_kernel<<<dim3(16, 3), 256, 0, stream>>>(Wl, Wr, Wm, Wt_l, Wt_r, Wt_m);

    // CSR build (inv needed by gemm_xl's permuted epilogue)
    hist_kernel<<<(E + 255) / 256, 256, 0, stream>>>(etgt, counts, E);
    scan_kernel<<<1, 1024, 0, stream>>>(counts, offs, NS);
    scatter_kernel<<<(E + 255) / 256, 256, 0, stream>>>(etgt, esrc, offs, cursor, inv, E);

    ln_relu_kernel<<<(NS + 3) / 4, 256, 0, stream>>>(prev, ln1g, ln1b, x_agg, NS);

    // xr = x_agg @ Wr + br (bf16 A, fp32 out)
    gemm256_kernel<0, 0, 1, 0><<<(NS + 127) / 128, 256, 0, stream>>>(
        x_agg, Wt_r, br, nullptr, nullptr, (void*)xr, NS);

    // xl = proj @ Wl + bl (fp32 A, bf16 out, CSR-permuted rows)
    gemm256_kernel<1, 0, 0, 1><<<(NP + 127) / 128, 256, 0, stream>>>(
        proj, Wt_l, bl, nullptr, inv, (void*)xl, NP);

    // fused edge softmax + aggregation + residual + LN2 + relu (streaming xl)
    aggregate_kernel<<<(NS + 3) / 4, 256, 0, stream>>>(
        xl, xr, prev, offs, att, gbias, ln2g, ln2b, x_skip, h2, NS);

    // out = x_skip + h2 @ mlp_W + mlp_b (bf16 A)
    gemm256_kernel<0, 1, 1, 0><<<(NS + 127) / 128, 256, 0, stream>>>(
        h2, Wt_m, mb, x_skip, nullptr, d_out, NS);
}